// Round 1
// baseline (1670.915 us; speedup 1.0000x reference)
//
#include <hip/hip_runtime.h>
#include <math.h>

// ---------------- init: zero accumulators, deg = 1.0 (self-loop) ------------
__global__ __launch_bounds__(256) void k_init(float* __restrict__ agg1,
                                              float* __restrict__ deg,
                                              float* __restrict__ agg2,
                                              int n64, int n) {
    int i = blockIdx.x * 256 + threadIdx.x;
    int stride = gridDim.x * 256;
    for (int idx = i; idx < n64; idx += stride) {
        agg1[idx] = 0.0f;
        if (idx < n) { deg[idx] = 1.0f; agg2[idx] = 0.0f; }
    }
}

// ---------------- degree: in-degree at dst ----------------------------------
__global__ __launch_bounds__(256) void k_deg(const int* __restrict__ dst,
                                             float* __restrict__ deg, int E) {
    int e = blockIdx.x * 256 + threadIdx.x;
    if (e < E) atomicAdd(&deg[dst[e]], 1.0f);
}

// ---------------- GEMM1: h1 = x @ W1  [N,128]@[128,64] ----------------------
// W1^T staged in LDS (stride 132 -> uniform bank coverage for b128 reads).
// 4 waves/block, 8 rows per wave; x-row loads are wave-uniform (scalar loads).
__global__ __launch_bounds__(256) void k_gemm1(const float* __restrict__ x,
                                               const float* __restrict__ W1,
                                               float* __restrict__ h1, int N) {
    __shared__ float Wt[64 * 132];
    int tid = threadIdx.x;
    for (int i = tid; i < 128 * 64; i += 256) {
        int j = i >> 6, k = i & 63;
        Wt[k * 132 + j] = W1[i];
    }
    __syncthreads();

    int lane = tid & 63;
    int wib  = __builtin_amdgcn_readfirstlane(tid >> 6);
    int wid  = blockIdx.x * 4 + wib;
    int nwaves = gridDim.x * 4;
    const float* wrow = &Wt[lane * 132];

    for (int n0 = wid * 8; n0 < N; n0 += nwaves * 8) {
        float acc[8] = {0.f, 0.f, 0.f, 0.f, 0.f, 0.f, 0.f, 0.f};
        for (int j = 0; j < 128; j += 4) {
            float4 w4 = *(const float4*)(wrow + j);
#pragma unroll
            for (int r = 0; r < 8; ++r) {
                const float* xr = &x[(size_t)(n0 + r) * 128 + j];  // uniform -> s_load
                acc[r] = fmaf(xr[0], w4.x, acc[r]);
                acc[r] = fmaf(xr[1], w4.y, acc[r]);
                acc[r] = fmaf(xr[2], w4.z, acc[r]);
                acc[r] = fmaf(xr[3], w4.w, acc[r]);
            }
        }
#pragma unroll
        for (int r = 0; r < 8; ++r)
            h1[(size_t)(n0 + r) * 64 + lane] = acc[r];
    }
}

// ---------------- scatter1: agg1[dst] += h1[src] * norm ---------------------
// 16 threads per edge, float4 gather + 4 atomic adds. Self-loops appended.
__global__ __launch_bounds__(256) void k_scatter1(const int* __restrict__ src,
                                                  const int* __restrict__ dst,
                                                  const float* __restrict__ deg,
                                                  const float* __restrict__ h1,
                                                  float* __restrict__ agg1,
                                                  int E, int N) {
    int gid = blockIdx.x * 256 + threadIdx.x;
    int total = (E + N) << 4;
    if (gid >= total) return;
    int eg = gid >> 4;
    int f  = (gid & 15) << 2;
    int s, d;
    if (eg < E) { s = src[eg]; d = dst[eg]; }
    else        { s = eg - E; d = s; }
    float nrm = rsqrtf(deg[s]) * rsqrtf(deg[d]);
    const float4 hv = *(const float4*)&h1[((size_t)s << 6) + f];
    float* ap = &agg1[((size_t)d << 6) + f];
    atomicAdd(ap + 0, hv.x * nrm);
    atomicAdd(ap + 1, hv.y * nrm);
    atomicAdd(ap + 2, hv.z * nrm);
    atomicAdd(ap + 3, hv.w * nrm);
}

// ---------------- layer2: h2[n] = relu(agg1[n]+b1) . W2 ---------------------
// one wave per node, shuffle reduce over 64 lanes
__global__ __launch_bounds__(256) void k_layer2(const float* __restrict__ agg1,
                                                const float* __restrict__ b1,
                                                const float* __restrict__ W2,
                                                float* __restrict__ h2, int N) {
    int lane = threadIdx.x & 63;
    int n = blockIdx.x * 4 + (threadIdx.x >> 6);
    if (n >= N) return;
    float a = agg1[((size_t)n << 6) + lane] + b1[lane];
    a = fmaxf(a, 0.0f);
    float p = a * W2[lane];
#pragma unroll
    for (int off = 32; off > 0; off >>= 1) p += __shfl_down(p, off);
    if (lane == 0) h2[n] = p;
}

// ---------------- scatter2: agg2[dst] += h2[src] * norm ---------------------
__global__ __launch_bounds__(256) void k_scatter2(const int* __restrict__ src,
                                                  const int* __restrict__ dst,
                                                  const float* __restrict__ deg,
                                                  const float* __restrict__ h2,
                                                  float* __restrict__ agg2,
                                                  int E, int N) {
    int e = blockIdx.x * 256 + threadIdx.x;
    int total = E + N;
    if (e >= total) return;
    int s, d;
    if (e < E) { s = src[e]; d = dst[e]; }
    else       { s = e - E; d = s; }
    float nrm = rsqrtf(deg[s]) * rsqrtf(deg[d]);
    atomicAdd(&agg2[d], h2[s] * nrm);
}

// ---------------- final: sigmoid(agg2 + b2) ---------------------------------
__global__ __launch_bounds__(256) void k_final(const float* __restrict__ agg2,
                                               const float* __restrict__ b2,
                                               float* __restrict__ out, int N) {
    int n = blockIdx.x * 256 + threadIdx.x;
    if (n < N) {
        float v = agg2[n] + b2[0];
        out[n] = 1.0f / (1.0f + expf(-v));
    }
}

extern "C" void kernel_launch(void* const* d_in, const int* in_sizes, int n_in,
                              void* d_out, int out_size, void* d_ws, size_t ws_size,
                              hipStream_t stream) {
    const float* x  = (const float*)d_in[0];
    const int*   ei = (const int*)d_in[1];   // [2, E] row-major, int32
    const float* W1 = (const float*)d_in[2];
    const float* b1 = (const float*)d_in[3];
    const float* W2 = (const float*)d_in[4];
    const float* b2 = (const float*)d_in[5];
    float* out = (float*)d_out;

    int N = in_sizes[0] / 128;
    int E = in_sizes[1] / 2;
    const int* src = ei;
    const int* dst = ei + E;

    // workspace layout (floats)
    float* w = (float*)d_ws;
    size_t Npad = ((size_t)N + 127) & ~(size_t)127;
    float* deg  = w;
    float* h1   = deg + Npad;
    float* agg1 = h1 + (size_t)N * 64;
    float* h2   = agg1 + (size_t)N * 64;
    float* agg2 = h2 + Npad;

    int n64 = N * 64;
    k_init<<<2048, 256, 0, stream>>>(agg1, deg, agg2, n64, N);
    k_deg<<<(E + 255) / 256, 256, 0, stream>>>(dst, deg, E);
    k_gemm1<<<(N + 31) / 32, 256, 0, stream>>>(x, W1, h1, N);
    long long tot1 = (long long)(E + N) * 16;
    k_scatter1<<<(int)((tot1 + 255) / 256), 256, 0, stream>>>(src, dst, deg, h1, agg1, E, N);
    k_layer2<<<(N + 3) / 4, 256, 0, stream>>>(agg1, b1, W2, h2, N);
    k_scatter2<<<(E + N + 255) / 256, 256, 0, stream>>>(src, dst, deg, h2, agg2, E, N);
    k_final<<<(N + 255) / 256, 256, 0, stream>>>(agg2, b2, out, N);
}

// Round 2
// 325.055 us; speedup vs baseline: 5.1404x; 5.1404x over previous
//
#include <hip/hip_runtime.h>
#include <math.h>

// ---------------- zero int counts -------------------------------------------
__global__ __launch_bounds__(256) void k_zero(int* __restrict__ cnt, int N) {
    int i = blockIdx.x * 256 + threadIdx.x;
    if (i < N) cnt[i] = 0;
}

// ---------------- histogram of dst ------------------------------------------
__global__ __launch_bounds__(256) void k_count(const int* __restrict__ dst,
                                               int* __restrict__ cnt, int E) {
    int e = blockIdx.x * 256 + threadIdx.x;
    if (e < E) atomicAdd(&cnt[dst[e]], 1);
}

// ---------------- scan phase 1: per-block exclusive scan --------------------
__global__ __launch_bounds__(256) void k_scan1(const int* __restrict__ cnt,
                                               int* __restrict__ excl,
                                               int* __restrict__ partials, int N) {
    __shared__ int sm[256];
    int t = threadIdx.x;
    int i = blockIdx.x * 256 + t;
    int v = (i < N) ? cnt[i] : 0;
    sm[t] = v;
    __syncthreads();
    for (int off = 1; off < 256; off <<= 1) {
        int x = sm[t];
        int y = (t >= off) ? sm[t - off] : 0;
        __syncthreads();
        sm[t] = x + y;
        __syncthreads();
    }
    int incl = sm[t];
    if (i < N) excl[i] = incl - v;
    if (t == 255) partials[blockIdx.x] = incl;
}

// ---------------- scan phase 2: scan block totals (single block) ------------
__global__ __launch_bounds__(256) void k_scan2(int* __restrict__ partials, int nb) {
    __shared__ int sm[256];
    __shared__ int run;
    int t = threadIdx.x;
    if (t == 0) run = 0;
    __syncthreads();
    for (int c = 0; c < nb; c += 256) {
        int v = (c + t < nb) ? partials[c + t] : 0;
        sm[t] = v;
        __syncthreads();
        for (int off = 1; off < 256; off <<= 1) {
            int x = sm[t];
            int y = (t >= off) ? sm[t - off] : 0;
            __syncthreads();
            sm[t] = x + y;
            __syncthreads();
        }
        int incl = sm[t];
        int base = run;
        if (c + t < nb) partials[c + t] = base + incl - v;
        __syncthreads();
        if (t == 0) run += sm[255];
        __syncthreads();
    }
}

// ---------------- scan phase 3: add offsets; cursor copy; dinv --------------
__global__ __launch_bounds__(256) void k_scan3(int* __restrict__ rowptr,
                                               const int* __restrict__ partials,
                                               int* __restrict__ cursor,
                                               const int* __restrict__ cnt,
                                               float* __restrict__ dinv,
                                               int N, int E) {
    int i = blockIdx.x * 256 + threadIdx.x;
    if (i < N) {
        int v = rowptr[i] + partials[i >> 8];
        rowptr[i] = v;
        cursor[i] = v;
        dinv[i] = rsqrtf((float)(cnt[i] + 1));  // +1 self-loop
    }
    if (i == 0) rowptr[N] = E;
}

// ---------------- fill CSR col (src grouped by dst) -------------------------
__global__ __launch_bounds__(256) void k_fill(const int* __restrict__ src,
                                              const int* __restrict__ dst,
                                              int* __restrict__ cursor,
                                              int* __restrict__ col, int E) {
    int e = blockIdx.x * 256 + threadIdx.x;
    if (e < E) {
        int p = atomicAdd(&cursor[dst[e]], 1);
        col[p] = src[e];
    }
}

// ---------------- GEMM1: h1s = (x @ W1) * dinv[row] -------------------------
// W1^T staged in LDS (stride 132); 4 waves/block, 8 rows/wave; x loads
// wave-uniform -> scalar loads.
__global__ __launch_bounds__(256) void k_gemm1s(const float* __restrict__ x,
                                                const float* __restrict__ W1,
                                                const float* __restrict__ dinv,
                                                float* __restrict__ h1s, int N) {
    __shared__ float Wt[64 * 132];
    int tid = threadIdx.x;
    for (int i = tid; i < 128 * 64; i += 256) {
        int j = i >> 6, k = i & 63;
        Wt[k * 132 + j] = W1[i];
    }
    __syncthreads();

    int lane = tid & 63;
    int wib  = __builtin_amdgcn_readfirstlane(tid >> 6);
    int wid  = blockIdx.x * 4 + wib;
    int nwaves = gridDim.x * 4;
    const float* wrow = &Wt[lane * 132];

    for (int n0 = wid * 8; n0 + 8 <= N; n0 += nwaves * 8) {
        float acc[8] = {0.f, 0.f, 0.f, 0.f, 0.f, 0.f, 0.f, 0.f};
        for (int j = 0; j < 128; j += 4) {
            float4 w4 = *(const float4*)(wrow + j);
#pragma unroll
            for (int r = 0; r < 8; ++r) {
                const float* xr = &x[(size_t)(n0 + r) * 128 + j];
                acc[r] = fmaf(xr[0], w4.x, acc[r]);
                acc[r] = fmaf(xr[1], w4.y, acc[r]);
                acc[r] = fmaf(xr[2], w4.z, acc[r]);
                acc[r] = fmaf(xr[3], w4.w, acc[r]);
            }
        }
#pragma unroll
        for (int r = 0; r < 8; ++r)
            h1s[(size_t)(n0 + r) * 64 + lane] = acc[r] * dinv[n0 + r];
    }
}

// ---------------- gather1 + layer2 fused ------------------------------------
// wave per dst node, lane = feature. agg1 = dinv[d]*(h1s[d] + sum h1s[col]);
// then h2s[d] = dinv[d] * (relu(agg1+b1) . W2)
__global__ __launch_bounds__(256) void k_gather1(const float* __restrict__ h1s,
                                                 const int* __restrict__ rowptr,
                                                 const int* __restrict__ col,
                                                 const float* __restrict__ dinv,
                                                 const float* __restrict__ b1,
                                                 const float* __restrict__ W2,
                                                 float* __restrict__ h2s, int N) {
    int lane = threadIdx.x & 63;
    int d = blockIdx.x * 4 + (threadIdx.x >> 6);
    if (d >= N) return;
    d = __builtin_amdgcn_readfirstlane(d);
    int beg = rowptr[d], end = rowptr[d + 1];
    float acc = h1s[((size_t)d << 6) + lane];  // self-loop term
    int e = beg;
    for (; e + 4 <= end; e += 4) {
        int s0 = col[e], s1 = col[e + 1], s2 = col[e + 2], s3 = col[e + 3];
        float v0 = h1s[((size_t)s0 << 6) + lane];
        float v1 = h1s[((size_t)s1 << 6) + lane];
        float v2 = h1s[((size_t)s2 << 6) + lane];
        float v3 = h1s[((size_t)s3 << 6) + lane];
        acc += v0 + v1 + v2 + v3;
    }
    for (; e < end; ++e) acc += h1s[((size_t)col[e] << 6) + lane];

    float dv = dinv[d];
    float a = fmaxf(fmaf(acc, dv, b1[lane]), 0.0f);
    float p = a * W2[lane];
#pragma unroll
    for (int off = 32; off > 0; off >>= 1) p += __shfl_down(p, off);
    if (lane == 0) h2s[d] = p * dv;
}

// ---------------- gather2 + bias + sigmoid ----------------------------------
__global__ __launch_bounds__(256) void k_gather2(const float* __restrict__ h2s,
                                                 const int* __restrict__ rowptr,
                                                 const int* __restrict__ col,
                                                 const float* __restrict__ dinv,
                                                 const float* __restrict__ b2,
                                                 float* __restrict__ out, int N) {
    int d = blockIdx.x * 256 + threadIdx.x;
    if (d >= N) return;
    float acc = h2s[d];  // self-loop
    int end = rowptr[d + 1];
    for (int e = rowptr[d]; e < end; ++e) acc += h2s[col[e]];
    float v = fmaf(acc, dinv[d], b2[0]);
    out[d] = 1.0f / (1.0f + expf(-v));
}

extern "C" void kernel_launch(void* const* d_in, const int* in_sizes, int n_in,
                              void* d_out, int out_size, void* d_ws, size_t ws_size,
                              hipStream_t stream) {
    const float* x  = (const float*)d_in[0];
    const int*   ei = (const int*)d_in[1];   // [2, E] row-major, int32
    const float* W1 = (const float*)d_in[2];
    const float* b1 = (const float*)d_in[3];
    const float* W2 = (const float*)d_in[4];
    const float* b2 = (const float*)d_in[5];
    float* out = (float*)d_out;

    int N = in_sizes[0] / 128;
    int E = in_sizes[1] / 2;
    const int* src = ei;
    const int* dst = ei + E;

    // workspace layout
    size_t Npad = ((size_t)N + 255) & ~(size_t)255;
    int* cnt      = (int*)d_ws;               // N
    int* rowptr   = cnt + Npad;               // N+1
    int* cursor   = rowptr + Npad;            // N
    int* partials = cursor + Npad;            // <=1024
    int* colv     = partials + 1024;          // E
    size_t Epad = ((size_t)E + 255) & ~(size_t)255;
    float* dinv   = (float*)(colv + Epad);    // N
    float* h2s    = dinv + Npad;              // N
    float* h1s    = h2s + Npad;               // N*64

    int nbN = (N + 255) / 256;
    int nbE = (E + 255) / 256;

    k_zero  <<<nbN, 256, 0, stream>>>(cnt, N);
    k_count <<<nbE, 256, 0, stream>>>(dst, cnt, E);
    k_scan1 <<<nbN, 256, 0, stream>>>(cnt, rowptr, partials, N);
    k_scan2 <<<1,   256, 0, stream>>>(partials, nbN);
    k_scan3 <<<nbN, 256, 0, stream>>>(rowptr, partials, cursor, cnt, dinv, N, E);
    k_fill  <<<nbE, 256, 0, stream>>>(src, dst, cursor, colv, E);
    k_gemm1s<<<(N + 31) / 32, 256, 0, stream>>>(x, W1, dinv, h1s, N);
    k_gather1<<<(N + 3) / 4, 256, 0, stream>>>(h1s, rowptr, colv, dinv, b1, W2, h2s, N);
    k_gather2<<<nbN, 256, 0, stream>>>(h2s, rowptr, colv, dinv, b2, out, N);
}

// Round 3
// 189.710 us; speedup vs baseline: 8.8077x; 1.7134x over previous
//
#include <hip/hip_runtime.h>
#include <math.h>

#define NBINS 512  // buckets over dst>>8 (covers N up to 131072)

// ---------------- zero bucket counters --------------------------------------
__global__ __launch_bounds__(512) void k_zero512(int* __restrict__ bcnt) {
    bcnt[threadIdx.x] = 0;
}

// ---------------- bucket histogram of dst>>8 (LDS-privatized) ---------------
__global__ __launch_bounds__(256) void k_bcnt(const int* __restrict__ dst,
                                              int* __restrict__ bcnt, int E) {
    __shared__ int lh[NBINS];
    for (int i = threadIdx.x; i < NBINS; i += 256) lh[i] = 0;
    __syncthreads();
    int stride = gridDim.x * 256;
    for (int e = blockIdx.x * 256 + threadIdx.x; e < E; e += stride)
        atomicAdd(&lh[dst[e] >> 8], 1);
    __syncthreads();
    for (int i = threadIdx.x; i < NBINS; i += 256) {
        int v = lh[i];
        if (v) atomicAdd(&bcnt[i], v);
    }
}

// ---------------- scan 512 bucket counts (single block) ---------------------
__global__ __launch_bounds__(512) void k_bscan(const int* __restrict__ bcnt,
                                               int* __restrict__ bbase,
                                               int* __restrict__ bcursor) {
    __shared__ int sm[NBINS];
    int t = threadIdx.x;
    int v = bcnt[t];
    sm[t] = v;
    __syncthreads();
    for (int off = 1; off < NBINS; off <<= 1) {
        int x = sm[t];
        int y = (t >= off) ? sm[t - off] : 0;
        __syncthreads();
        sm[t] = x + y;
        __syncthreads();
    }
    int excl = sm[t] - v;
    bbase[t] = excl;
    bcursor[t] = excl;
    if (t == NBINS - 1) bbase[NBINS] = sm[t];
}

// ---------------- bucket scatter: packed (dst,src) -> bucket-grouped --------
// 4096 edges/block; per-block LDS histogram, one reserving atomic per
// (block,bin), then writes land in ~64B runs per bin.
__global__ __launch_bounds__(256) void k_bscatter(const int* __restrict__ src,
                                                  const int* __restrict__ dst,
                                                  int* __restrict__ bcursor,
                                                  unsigned long long* __restrict__ ebuf,
                                                  int E) {
    __shared__ int lh[NBINS];
    __shared__ int lbase[NBINS];
    for (int i = threadIdx.x; i < NBINS; i += 256) lh[i] = 0;
    __syncthreads();
    int base = blockIdx.x * 4096;
    int t = threadIdx.x;
    int s_[16], d_[16], r_[16];
#pragma unroll
    for (int k = 0; k < 16; ++k) {
        int e = base + k * 256 + t;
        if (e < E) {
            int dd = dst[e];
            d_[k] = dd;
            s_[k] = src[e];
            r_[k] = atomicAdd(&lh[dd >> 8], 1);
        }
    }
    __syncthreads();
    for (int i = threadIdx.x; i < NBINS; i += 256) {
        int c = lh[i];
        lbase[i] = c ? atomicAdd(&bcursor[i], c) : 0;
    }
    __syncthreads();
#pragma unroll
    for (int k = 0; k < 16; ++k) {
        int e = base + k * 256 + t;
        if (e < E) {
            int b = d_[k] >> 8;
            ebuf[lbase[b] + r_[k]] =
                ((unsigned long long)(unsigned)d_[k] << 32) | (unsigned)s_[k];
        }
    }
}

// ---------------- per-bucket CSR build: rowptr, dinv, col -------------------
// one block per bucket; all histogram/scan/scatter local to a ~13KB region.
__global__ __launch_bounds__(256) void k_bucket_csr(const unsigned long long* __restrict__ ebuf,
                                                    const int* __restrict__ bbase,
                                                    int* __restrict__ rowptr,
                                                    float* __restrict__ dinv,
                                                    int* __restrict__ col,
                                                    int N, int E) {
    __shared__ int lh[256];
    __shared__ int lex[256];
    __shared__ int lcur[256];
    int b = blockIdx.x;
    int t = threadIdx.x;
    int beg = bbase[b], end = bbase[b + 1];
    lh[t] = 0;
    __syncthreads();
    for (int e = beg + t; e < end; e += 256)
        atomicAdd(&lh[(int)(ebuf[e] >> 32) & 255], 1);
    __syncthreads();
    lex[t] = lh[t];
    __syncthreads();
    for (int off = 1; off < 256; off <<= 1) {
        int x = lex[t];
        int y = (t >= off) ? lex[t - off] : 0;
        __syncthreads();
        lex[t] = x + y;
        __syncthreads();
    }
    int excl = lex[t] - lh[t];
    int node = (b << 8) + t;
    if (node < N) {
        rowptr[node] = beg + excl;
        dinv[node] = rsqrtf((float)(lh[t] + 1));  // +1 self-loop
    }
    lcur[t] = beg + excl;
    if (b == 0 && t == 0) rowptr[N] = E;
    __syncthreads();
    for (int e = beg + t; e < end; e += 256) {
        unsigned long long v = ebuf[e];
        int p = atomicAdd(&lcur[(int)(v >> 32) & 255], 1);
        col[p] = (int)(unsigned)v;
    }
}

// ---------------- GEMM1: h1s = (x @ W1) * dinv[row] -------------------------
__global__ __launch_bounds__(256) void k_gemm1s(const float* __restrict__ x,
                                                const float* __restrict__ W1,
                                                const float* __restrict__ dinv,
                                                float* __restrict__ h1s, int N) {
    __shared__ float Wt[64 * 132];
    int tid = threadIdx.x;
    for (int i = tid; i < 128 * 64; i += 256) {
        int j = i >> 6, k = i & 63;
        Wt[k * 132 + j] = W1[i];
    }
    __syncthreads();

    int lane = tid & 63;
    int wib  = __builtin_amdgcn_readfirstlane(tid >> 6);
    int wid  = blockIdx.x * 4 + wib;
    int nwaves = gridDim.x * 4;
    const float* wrow = &Wt[lane * 132];

    for (int n0 = wid * 8; n0 + 8 <= N; n0 += nwaves * 8) {
        float acc[8] = {0.f, 0.f, 0.f, 0.f, 0.f, 0.f, 0.f, 0.f};
        for (int j = 0; j < 128; j += 4) {
            float4 w4 = *(const float4*)(wrow + j);
#pragma unroll
            for (int r = 0; r < 8; ++r) {
                const float* xr = &x[(size_t)(n0 + r) * 128 + j];
                acc[r] = fmaf(xr[0], w4.x, acc[r]);
                acc[r] = fmaf(xr[1], w4.y, acc[r]);
                acc[r] = fmaf(xr[2], w4.z, acc[r]);
                acc[r] = fmaf(xr[3], w4.w, acc[r]);
            }
        }
#pragma unroll
        for (int r = 0; r < 8; ++r)
            h1s[(size_t)(n0 + r) * 64 + lane] = acc[r] * dinv[n0 + r];
    }
}

// ---------------- gather1 + layer2 fused ------------------------------------
__global__ __launch_bounds__(256) void k_gather1(const float* __restrict__ h1s,
                                                 const int* __restrict__ rowptr,
                                                 const int* __restrict__ col,
                                                 const float* __restrict__ dinv,
                                                 const float* __restrict__ b1,
                                                 const float* __restrict__ W2,
                                                 float* __restrict__ h2s, int N) {
    int lane = threadIdx.x & 63;
    int d = blockIdx.x * 4 + (threadIdx.x >> 6);
    if (d >= N) return;
    d = __builtin_amdgcn_readfirstlane(d);
    int beg = rowptr[d], end = rowptr[d + 1];
    float acc = h1s[((size_t)d << 6) + lane];  // self-loop term
    int e = beg;
    for (; e + 4 <= end; e += 4) {
        int s0 = col[e], s1 = col[e + 1], s2 = col[e + 2], s3 = col[e + 3];
        float v0 = h1s[((size_t)s0 << 6) + lane];
        float v1 = h1s[((size_t)s1 << 6) + lane];
        float v2 = h1s[((size_t)s2 << 6) + lane];
        float v3 = h1s[((size_t)s3 << 6) + lane];
        acc += v0 + v1 + v2 + v3;
    }
    for (; e < end; ++e) acc += h1s[((size_t)col[e] << 6) + lane];

    float dv = dinv[d];
    float a = fmaxf(fmaf(acc, dv, b1[lane]), 0.0f);
    float p = a * W2[lane];
#pragma unroll
    for (int off = 32; off > 0; off >>= 1) p += __shfl_down(p, off);
    if (lane == 0) h2s[d] = p * dv;
}

// ---------------- gather2 + bias + sigmoid ----------------------------------
__global__ __launch_bounds__(256) void k_gather2(const float* __restrict__ h2s,
                                                 const int* __restrict__ rowptr,
                                                 const int* __restrict__ col,
                                                 const float* __restrict__ dinv,
                                                 const float* __restrict__ b2,
                                                 float* __restrict__ out, int N) {
    int d = blockIdx.x * 256 + threadIdx.x;
    if (d >= N) return;
    float acc = h2s[d];  // self-loop
    int end = rowptr[d + 1];
    for (int e = rowptr[d]; e < end; ++e) acc += h2s[col[e]];
    float v = fmaf(acc, dinv[d], b2[0]);
    out[d] = 1.0f / (1.0f + expf(-v));
}

extern "C" void kernel_launch(void* const* d_in, const int* in_sizes, int n_in,
                              void* d_out, int out_size, void* d_ws, size_t ws_size,
                              hipStream_t stream) {
    const float* x  = (const float*)d_in[0];
    const int*   ei = (const int*)d_in[1];   // [2, E] row-major, int32
    const float* W1 = (const float*)d_in[2];
    const float* b1 = (const float*)d_in[3];
    const float* W2 = (const float*)d_in[4];
    const float* b2 = (const float*)d_in[5];
    float* out = (float*)d_out;

    int N = in_sizes[0] / 128;
    int E = in_sizes[1] / 2;
    const int* src = ei;
    const int* dst = ei + E;

    // ---- workspace layout (ebuf dead after k_bucket_csr -> h1s reuses it) --
    char* w = (char*)d_ws;
    size_t region0 = (size_t)N * 64 * 4;                     // h1s bytes
    size_t ebytes  = (size_t)E * 8;                          // ebuf bytes
    if (ebytes > region0) region0 = ebytes;
    region0 = (region0 + 255) & ~(size_t)255;

    float* h1s  = (float*)w;
    unsigned long long* ebuf = (unsigned long long*)w;
    int* colv   = (int*)(w + region0);
    int* rowptr = colv + (((size_t)E + 255) & ~(size_t)255);
    size_t Npad = ((size_t)N + 511) & ~(size_t)511;
    float* dinv = (float*)(rowptr + Npad + 512);
    float* h2s  = dinv + Npad;
    int* bcnt   = (int*)(h2s + Npad);
    int* bbase  = bcnt + NBINS;       // NBINS+1
    int* bcursor = bbase + NBINS + 8;

    int nbuck = (N + 255) >> 8;

    k_zero512  <<<1, 512, 0, stream>>>(bcnt);
    k_bcnt     <<<512, 256, 0, stream>>>(dst, bcnt, E);
    k_bscan    <<<1, 512, 0, stream>>>(bcnt, bbase, bcursor);
    k_bscatter <<<(E + 4095) / 4096, 256, 0, stream>>>(src, dst, bcursor, ebuf, E);
    k_bucket_csr<<<nbuck, 256, 0, stream>>>(ebuf, bbase, rowptr, dinv, colv, N, E);
    k_gemm1s   <<<(N + 31) / 32, 256, 0, stream>>>(x, W1, dinv, h1s, N);
    k_gather1  <<<(N + 3) / 4, 256, 0, stream>>>(h1s, rowptr, colv, dinv, b1, W2, h2s, N);
    k_gather2  <<<(N + 255) / 256, 256, 0, stream>>>(h2s, rowptr, colv, dinv, b2, out, N);
}